// Round 6
// baseline (445.185 us; speedup 1.0000x reference)
//
#include <hip/hip_runtime.h>
#include <hip/hip_bf16.h>
#include <math.h>

// Problem constants (QwenAttention: B=2,S=2048,E=2048,H=16,KV=4,D=128)
#define BB 2
#define SS 2048
#define EE 2048
#define HH 16
#define KVH 4
#define DD 128

typedef short short8 __attribute__((ext_vector_type(8)));
typedef float f32x4 __attribute__((ext_vector_type(4)));

__device__ __forceinline__ unsigned int f2bf1(float x) {
    union { float f; unsigned int u; } v; v.f = x;
    return (v.u + 0x7FFFu + ((v.u >> 16) & 1u)) >> 16;  // RNE bf16
}
__device__ __forceinline__ unsigned int packbf(float a, float b) {
    return f2bf1(a) | (f2bf1(b) << 16);
}
// async global->LDS, 16B per lane
__device__ __forceinline__ void gl_lds16(const void* g, void* l) {
    __builtin_amdgcn_global_load_lds(
        (const __attribute__((address_space(1))) unsigned int*)g,
        (__attribute__((address_space(3))) unsigned int*)l,
        16, 0, 0);
}

// DPP 16-lane butterfly reductions (VALU pipe, not LDS).
#define DPPF(x, ctrl) __int_as_float(__builtin_amdgcn_update_dpp( \
    0, __float_as_int(x), ctrl, 0xf, 0xf, true))
__device__ __forceinline__ float rmax16(float x) {
    x = fmaxf(x, DPPF(x, 0xB1));
    x = fmaxf(x, DPPF(x, 0x4E));
    x = fmaxf(x, DPPF(x, 0x141));
    x = fmaxf(x, DPPF(x, 0x140));
    return x;
}
__device__ __forceinline__ float rsum16(float x) {
    x += DPPF(x, 0xB1);
    x += DPPF(x, 0x4E);
    x += DPPF(x, 0x141);
    x += DPPF(x, 0x140);
    return x;
}

// ---------------------------------------------------------------------------
// Fused fp32->bf16 conversion of all inputs + bias concat, one launch.
// ---------------------------------------------------------------------------
__global__ __launch_bounds__(256) void cvt_all_kernel(
    const float* __restrict__ x,  const float* __restrict__ Wq,
    const float* __restrict__ Wk, const float* __restrict__ Wv,
    const float* __restrict__ Wo, const float* __restrict__ bq,
    const float* __restrict__ bk, const float* __restrict__ bv,
    unsigned short* __restrict__ xb, unsigned short* __restrict__ wqkv,
    unsigned short* __restrict__ wob, float* __restrict__ bqkv)
{
    long id = (long)blockIdx.x * 256 + threadIdx.x;
    const float* src; unsigned short* dst; long j;
    if (id < 2097152)      { j = id;           src = x;  dst = xb; }
    else if (id < 3145728) { j = id - 2097152; src = Wq; dst = wqkv; }
    else if (id < 3407872) { j = id - 3145728; src = Wk; dst = wqkv + 4194304; }
    else if (id < 3670016) { j = id - 3407872; src = Wv; dst = wqkv + 5242880; }
    else if (id < 4718592) { j = id - 3670016; src = Wo; dst = wob; }
    else if (id < 4719360) {
        long c = (id - 4718592) * 4;
#pragma unroll
        for (int e = 0; e < 4; ++e) {
            long cc = c + e;
            bqkv[cc] = (cc < 2048) ? bq[cc] : (cc < 2560 ? bk[cc - 2048] : bv[cc - 2560]);
        }
        return;
    } else return;
    float4 f = ((const float4*)src)[j];
    ((uint2*)dst)[j] = make_uint2(packbf(f.x, f.y), packbf(f.z, f.w));
}

// ---------------------------------------------------------------------------
// m97-style bf16 MFMA GEMM: C[M,N] = A[M,K] @ W[N,K]^T + bias[N]  (unchanged)
// ---------------------------------------------------------------------------
template <bool OUT_BF16>
__global__ __launch_bounds__(256) void gemm_mfma_kernel(
    const unsigned short* __restrict__ A, const unsigned short* __restrict__ W,
    const float* __restrict__ bias, void* __restrict__ Cout,
    int M, int N, int K)
{
    __shared__ unsigned short As[128 * 32];
    __shared__ unsigned short Bs[128 * 32];

    const int tid  = threadIdx.x;
    const int w    = tid >> 6;
    const int lane = tid & 63;
    const int quad = lane >> 4;
    const int l16  = lane & 15;
    const int wr   = w >> 1, wc = w & 1;
    const int m0 = blockIdx.y * 128, n0 = blockIdx.x * 128;

    f32x4 acc[4][4];
#pragma unroll
    for (int i = 0; i < 4; ++i)
#pragma unroll
        for (int j = 0; j < 4; ++j) acc[i][j] = (f32x4){0.f, 0.f, 0.f, 0.f};

    const unsigned short* Ag = A + (size_t)(m0 + w * 32 + (lane >> 2)) * K + (lane & 3) * 8;
    const unsigned short* Wg = W + (size_t)(n0 + w * 32 + (lane >> 2)) * K + (lane & 3) * 8;
    unsigned short* AsB = &As[(w * 32) * 32];
    unsigned short* BsB = &Bs[(w * 32) * 32];

    for (int k0 = 0; k0 < K; k0 += 32) {
        gl_lds16(Ag + k0, AsB);
        gl_lds16(Ag + k0 + (size_t)16 * K, AsB + 16 * 32);
        gl_lds16(Wg + k0, BsB);
        gl_lds16(Wg + k0 + (size_t)16 * K, BsB + 16 * 32);
        __syncthreads();

        short8 a_f[4], b_f[4];
#pragma unroll
        for (int i = 0; i < 4; ++i)
            a_f[i] = *(const short8*)&As[(wr * 64 + i * 16 + l16) * 32 + quad * 8];
#pragma unroll
        for (int j = 0; j < 4; ++j)
            b_f[j] = *(const short8*)&Bs[(wc * 64 + j * 16 + l16) * 32 + quad * 8];
#pragma unroll
        for (int i = 0; i < 4; ++i)
#pragma unroll
            for (int j = 0; j < 4; ++j)
                acc[i][j] = __builtin_amdgcn_mfma_f32_16x16x32_bf16(a_f[i], b_f[j], acc[i][j], 0, 0, 0);
        __syncthreads();
    }

    float bj[4];
#pragma unroll
    for (int j = 0; j < 4; ++j)
        bj[j] = bias ? bias[n0 + wc * 64 + j * 16 + l16] : 0.0f;
#pragma unroll
    for (int i = 0; i < 4; ++i) {
#pragma unroll
        for (int r = 0; r < 4; ++r) {
            size_t row = m0 + wr * 64 + i * 16 + quad * 4 + r;
#pragma unroll
            for (int j = 0; j < 4; ++j) {
                size_t col = n0 + wc * 64 + j * 16 + l16;
                float val = acc[i][j][r] + bj[j];
                if (OUT_BF16)
                    ((unsigned short*)Cout)[row * N + col] = (unsigned short)f2bf1(val);
                else
                    ((float*)Cout)[row * N + col] = val;
            }
        }
    }
}

// ---------------------------------------------------------------------------
// RoPE on bf16 qkv buffer [M, 3072]  (unchanged)
// ---------------------------------------------------------------------------
__global__ __launch_bounds__(64) void rope_kernel(unsigned short* __restrict__ qkv)
{
    int bix = blockIdx.x;
    int m, col;
    if (bix < 65536) { m = bix >> 4; col = (bix & 15) * 128; }
    else { int i = bix - 65536; m = i >> 2; col = 2048 + (i & 3) * 128; }
    int s = m & (SS - 1);
    int d = threadIdx.x;
    unsigned short* p = qkv + (size_t)m * 3072 + col;
    float inv_freq = expf(-(float)d * (logf(10000.0f) / 64.0f));
    float fr = (float)s * inv_freq;
    float c = cosf(fr), sn = sinf(fr);
    union { unsigned int u; float f; } x1, x2;
    x1.u = ((unsigned int)p[d]) << 16;
    x2.u = ((unsigned int)p[d + 64]) << 16;
    p[d]      = (unsigned short)f2bf1(x1.f * c - x2.f * sn);
    p[d + 64] = (unsigned short)f2bf1(x2.f * c + x1.f * sn);
}

// ---------------------------------------------------------------------------
// Flash attention v4: 512-thread blocks = 2 column-groups x 4 waves.
// BR=128 q-rows per block; each step covers BC=128 K-positions, group g
// handling the 64-col half g with its own (m,l,O) partials. Block processes
// q-tile pair {j, 15-j} -> EXACTLY 17 steps per block; grid 8x16x2 = 256
// blocks = 1 block/CU, 8 waves/CU, perfectly balanced.
// End-of-pass flash merge of the two groups' partials through LDS; each
// group finalizes its own output-column half.
// Swizzled LDS (conflict-free), register prefetch, DPP softmax reductions.
// qkv: [B*S, 3072] (q: h*128, k: 2048+kv*128, v: 2560+kv*128); o: [B*S, 2048].
// ---------------------------------------------------------------------------
__global__ __launch_bounds__(512, 2) void attn_mfma_kernel(
    const unsigned short* __restrict__ qkv, unsigned short* __restrict__ o)
{
    __shared__ unsigned int Ks_u[2][64 * 64];    // 32 KB (per-group 16 KB)
    __shared__ unsigned int Vs_u[2][128 * 32];   // 32 KB (per-group 16 KB)
    __shared__ unsigned short Ps[8][32 * 64];    // 32 KB (per-wave 4 KB)
    __shared__ float Ml[2][128][2];              //  2 KB (m,l exchange)

    const int tid  = threadIdx.x;
    const int g    = tid >> 8;          // column group 0/1
    const int tloc = tid & 255;
    const int w8   = tid >> 6;          // wave 0..7
    const int wg   = w8 & 3;            // wave within group
    const int lane = tid & 63;
    const int quad = lane >> 4;
    const int l16  = lane & 15;
    const int jp   = blockIdx.x;        // 0..7 (pair index)
    const int h    = blockIdx.y;
    const int b    = blockIdx.z;
    const int kv   = h >> 2;            // G = 4

    const float k2 = 0.12752789744920764f;  // (1/sqrt(128)) * log2(e)

    const unsigned short* kbase = qkv + (size_t)b * SS * 3072 + 2048 + kv * 128;
    const unsigned short* vbase = kbase + 512;
    unsigned int* Kg = Ks_u[g];
    unsigned int* Vg = Vs_u[g];

    const int kc  = tloc & 15;          // K chunk (8 dims)
    const int kp0 = tloc >> 4;          // K row base 0..15
    const int vpp = tloc >> 3;          // V pos-pair 0..31
    const int vd0 = (tloc & 7) * 16;    // V d-segment base

    for (int pass = 0; pass < 2; ++pass) {
        const int qt = pass ? (15 - jp) : jp;
        const int q0 = qt * 128;
        const int nt = qt + 1;          // BC=128 steps

        // ---- Q A-frags: 2 sets of 16 rows (both groups load the same Q) ----
        short8 qf[2][4];
#pragma unroll
        for (int s = 0; s < 2; ++s) {
            const unsigned short* qp =
                qkv + (size_t)(b * SS + q0 + wg * 32 + s * 16 + l16) * 3072 + h * 128 + quad * 8;
#pragma unroll
            for (int ks = 0; ks < 4; ++ks)
                qf[s][ks] = *(const short8*)(qp + ks * 32);
        }

        // ---- prefetch step 0 into regs (group's 64-col half) ----
        uint4 kpre[4], vpa[2], vpb[2];
        {
            const unsigned short* kg2 = kbase + (size_t)(g * 64 + kp0) * 3072 + kc * 8;
#pragma unroll
            for (int rr = 0; rr < 4; ++rr)
                kpre[rr] = *(const uint4*)(kg2 + (size_t)rr * 16 * 3072);
            const unsigned short* vg = vbase + (size_t)(g * 64 + 2 * vpp) * 3072 + vd0;
            vpa[0] = *(const uint4*)(vg);
            vpa[1] = *(const uint4*)(vg + 8);
            vpb[0] = *(const uint4*)(vg + 3072);
            vpb[1] = *(const uint4*)(vg + 3072 + 8);
        }

        float m_r[2][4], l_r[2][4];
        f32x4 Oacc[2][8];
#pragma unroll
        for (int s = 0; s < 2; ++s)
#pragma unroll
            for (int r = 0; r < 4; ++r) { m_r[s][r] = -1e30f; l_r[s][r] = 0.0f; }
#pragma unroll
        for (int s = 0; s < 2; ++s)
#pragma unroll
            for (int ot = 0; ot < 8; ++ot) Oacc[s][ot] = (f32x4){0.f, 0.f, 0.f, 0.f};

        for (int t = 0; t < nt; ++t) {
            __syncthreads();   // previous tile reads (or previous-pass merge reads) done

            // ---- staged regs -> LDS (swizzled, conflict-free) ----
#pragma unroll
            for (int rr = 0; rr < 4; ++rr) {
                int pos = kp0 + rr * 16;
                int key = (kp0 + rr) & 7;
                *(uint4*)&Kg[pos * 64 + (kc ^ key) * 4] = kpre[rr];
            }
            {
                const unsigned int* pa = (const unsigned int*)vpa;
                const unsigned int* pb = (const unsigned int*)vpb;
#pragma unroll
                for (int j = 0; j < 8; ++j) {
                    unsigned lo = __builtin_amdgcn_perm(pb[j], pa[j], 0x05040100);
                    unsigned hi = __builtin_amdgcn_perm(pb[j], pa[j], 0x07060302);
                    int d0 = vd0 + 2 * j;
                    int gg = d0 >> 4;
                    int k0 = (d0 + gg) & 7;
                    int k1 = (d0 + 1 + gg) & 7;
                    Vg[d0 * 32 + (((vpp >> 2) ^ k0) & 7) * 4 + (vpp & 3)] = lo;
                    Vg[(d0 + 1) * 32 + (((vpp >> 2) ^ k1) & 7) * 4 + (vpp & 3)] = hi;
                }
            }
            __syncthreads();

            // ---- prefetch step t+1 (completes during compute) ----
            if (t + 1 < nt) {
                const unsigned short* kg2 =
                    kbase + (size_t)((t + 1) * 128 + g * 64 + kp0) * 3072 + kc * 8;
#pragma unroll
                for (int rr = 0; rr < 4; ++rr)
                    kpre[rr] = *(const uint4*)(kg2 + (size_t)rr * 16 * 3072);
                const unsigned short* vg =
                    vbase + (size_t)((t + 1) * 128 + g * 64 + 2 * vpp) * 3072 + vd0;
                vpa[0] = *(const uint4*)(vg);
                vpa[1] = *(const uint4*)(vg + 8);
                vpb[0] = *(const uint4*)(vg + 3072);
                vpb[1] = *(const uint4*)(vg + 3072 + 8);
            }

            // ---- S = Q @ K^T: both row-sets share every K-frag read ----
            f32x4 S0[4], S1[4];
#pragma unroll
            for (int ct = 0; ct < 4; ++ct) {
                f32x4 s0 = (f32x4){0.f, 0.f, 0.f, 0.f};
                f32x4 s1 = (f32x4){0.f, 0.f, 0.f, 0.f};
                const int row = ct * 16 + l16;
                const int key = (l16 + ct) & 7;
#pragma unroll
                for (int ks = 0; ks < 4; ++ks) {
                    short8 kf = *(const short8*)&Kg[row * 64 + ((ks * 4 + quad) ^ key) * 4];
                    s0 = __builtin_amdgcn_mfma_f32_16x16x32_bf16(qf[0][ks], kf, s0, 0, 0, 0);
                    s1 = __builtin_amdgcn_mfma_f32_16x16x32_bf16(qf[1][ks], kf, s1, 0, 0, 0);
                }
                S0[ct] = s0; S1[ct] = s1;
            }

            // ---- causal mask (final step only; diagonal block) ----
            if (t == nt - 1) {
                const int rw = q0 + wg * 32 + quad * 4;
#pragma unroll
                for (int ct = 0; ct < 4; ++ct) {
                    const int col = t * 128 + g * 64 + ct * 16 + l16;
#pragma unroll
                    for (int r = 0; r < 4; ++r) {
                        if (col > rw + r)      S0[ct][r] = -1e30f;
                        if (col > rw + 16 + r) S1[ct][r] = -1e30f;
                    }
                }
            }

            // ---- online softmax per set (DPP reductions) ----
#pragma unroll
            for (int s = 0; s < 2; ++s) {
                f32x4* S = s ? S1 : S0;
#pragma unroll
                for (int r = 0; r < 4; ++r) {
                    float c0 = fmaxf(fmaxf(S[0][r], S[1][r]), fmaxf(S[2][r], S[3][r]));
                    c0 = rmax16(c0);
                    float mnew = fmaxf(m_r[s][r], c0);
                    float alpha = exp2f((m_r[s][r] - mnew) * k2);
                    m_r[s][r] = mnew;
                    float mh = mnew * k2;
                    float rs = 0.0f;
                    const int prow = s * 16 + quad * 4 + r;
                    const int pkey = prow & 7;
#pragma unroll
                    for (int ct = 0; ct < 4; ++ct) {
                        float p = exp2f(S[ct][r] * k2 - mh);
                        rs += p;
                        int chunk = ct * 2 + (l16 >> 3);
                        union { float f; unsigned u; } pu; pu.f = p;
                        Ps[w8][prow * 64 + (chunk ^ pkey) * 8 + (l16 & 7)] =
                            (unsigned short)((pu.u + 0x8000u) >> 16);
                    }
                    rs = rsum16(rs);
                    l_r[s][r] = l_r[s][r] * alpha + rs;
#pragma unroll
                    for (int ot = 0; ot < 8; ++ot) Oacc[s][ot][r] *= alpha;
                }
            }

            // ---- O += P @ V: both sets share every V-frag read ----
            {
                const int pk = l16 & 7;
                short8 pf00 = *(const short8*)&Ps[w8][(l16)      * 64 + ((quad)     ^ pk) * 8];
                short8 pf01 = *(const short8*)&Ps[w8][(l16)      * 64 + ((4 + quad) ^ pk) * 8];
                short8 pf10 = *(const short8*)&Ps[w8][(16 + l16) * 64 + ((quad)     ^ pk) * 8];
                short8 pf11 = *(const short8*)&Ps[w8][(16 + l16) * 64 + ((4 + quad) ^ pk) * 8];
#pragma unroll
                for (int ot = 0; ot < 8; ++ot) {
                    const int d = ot * 16 + l16;
                    const int vkey = (l16 + ot) & 7;
                    short8 v0 = *(const short8*)&Vg[d * 32 + ((quad) ^ vkey) * 4];
                    Oacc[0][ot] = __builtin_amdgcn_mfma_f32_16x16x32_bf16(pf00, v0, Oacc[0][ot], 0, 0, 0);
                    Oacc[1][ot] = __builtin_amdgcn_mfma_f32_16x16x32_bf16(pf10, v0, Oacc[1][ot], 0, 0, 0);
                    short8 v1 = *(const short8*)&Vg[d * 32 + ((4 + quad) ^ vkey) * 4];
                    Oacc[0][ot] = __builtin_amdgcn_mfma_f32_16x16x32_bf16(pf01, v1, Oacc[0][ot], 0, 0, 0);
                    Oacc[1][ot] = __builtin_amdgcn_mfma_f32_16x16x32_bf16(pf11, v1, Oacc[1][ot], 0, 0, 0);
                }
            }
        }

        // ---- flash-merge the two groups' partials ----
        // Group g finalizes output cols [g*64, g*64+64) (ot g*4 .. g*4+3).
        // Each group exports its NON-finalized half + (m,l); then imports the
        // counterpart's partial for its own half.
        __syncthreads();   // all K/V LDS reads done -> safe to reuse as exchange
        {
            float* Ox = g ? (float*)Vs_u : (float*)Ks_u;  // write target: own buffer
            const int otb = (1 - g) * 4;                  // the half we export
#pragma unroll
            for (int s = 0; s < 2; ++s) {
                const int row = wg * 32 + s * 16 + quad * 4;
#pragma unroll
                for (int r = 0; r < 4; ++r) {
#pragma unroll
                    for (int oo = 0; oo < 4; ++oo)
                        Ox[(row + r) * 64 + oo * 16 + l16] = Oacc[s][otb + oo][r];
                    if (l16 == 0) {
                        Ml[g][row + r][0] = m_r[s][r];
                        Ml[g][row + r][1] = l_r[s][r];
                    }
                }
            }
        }
        __syncthreads();
        {
            const float* Oi = g ? (const float*)Ks_u : (const float*)Vs_u;  // counterpart's export
            const int go = 1 - g;
            const int otb = g * 4;                        // the half we finalize
#pragma unroll
            for (int s = 0; s < 2; ++s) {
                const int row0 = wg * 32 + s * 16 + quad * 4;
#pragma unroll
                for (int r = 0; r < 4; ++r) {
                    const int row = row0 + r;
                    float mo = Ml[go][row][0];
                    float lo2 = Ml[go][row][1];
                    float mm = fmaxf(m_r[s][r], mo);
                    float cw = exp2f((m_r[s][r] - mm) * k2);
                    float co = exp2f((mo - mm) * k2);
                    float inv = 1.0f / (l_r[s][r] * cw + lo2 * co);
                    unsigned short* ob =
                        o + (size_t)(b * SS + q0 + row) * 2048 + h * 128 + g * 64 + l16;
#pragma unroll
                    for (int oo = 0; oo < 4; ++oo) {
                        float val = (Oacc[s][otb + oo][r] * cw +
                                     Oi[row * 64 + oo * 16 + l16] * co) * inv;
                        ob[oo * 16] = (unsigned short)f2bf1(val);
                    }
                }
            }
        }
        // loop top's __syncthreads() protects exchange region before next pass
    }
}

// ---------------------------------------------------------------------------
extern "C" void kernel_launch(void* const* d_in, const int* in_sizes, int n_in,
                              void* d_out, int out_size, void* d_ws, size_t ws_size,
                              hipStream_t stream)
{
    const float* x  = (const float*)d_in[0];
    const float* Wq = (const float*)d_in[1];
    const float* bq = (const float*)d_in[2];
    const float* Wk = (const float*)d_in[3];
    const float* bk = (const float*)d_in[4];
    const float* Wv = (const float*)d_in[5];
    const float* bv = (const float*)d_in[6];
    const float* Wo = (const float*)d_in[7];
    float* out = (float*)d_out;

    const int M = BB * SS;  // 4096
    char* wsb = (char*)d_ws;
    unsigned short* xb   = (unsigned short*)wsb;  wsb += (size_t)M * EE * 2;
    unsigned short* wqkv = (unsigned short*)wsb;  wsb += (size_t)3072 * EE * 2;
    unsigned short* wob  = (unsigned short*)wsb;  wsb += (size_t)EE * EE * 2;
    unsigned short* qkvb = (unsigned short*)wsb;  wsb += (size_t)M * 3072 * 2;
    unsigned short* abb  = (unsigned short*)wsb;  wsb += (size_t)M * 2048 * 2;
    float* bqkv = (float*)wsb;

    cvt_all_kernel<<<18435, 256, 0, stream>>>(x, Wq, Wk, Wv, Wo, bq, bk, bv,
                                              xb, wqkv, wob, bqkv);

    gemm_mfma_kernel<true><<<dim3(3072 / 128, M / 128), 256, 0, stream>>>(
        xb, wqkv, bqkv, qkvb, M, 3072, EE);

    rope_kernel<<<M * HH + M * KVH, 64, 0, stream>>>(qkvb);

    // flash attention: 8 balanced q-tile pairs x 16 heads x 2 batch, 512 thr
    attn_mfma_kernel<<<dim3(8, HH, BB), 512, 0, stream>>>(qkvb, abb);

    gemm_mfma_kernel<false><<<dim3(EE / 128, M / 128), 256, 0, stream>>>(
        abb, wob, nullptr, out, M, EE, 2048);
}

// Round 7
// 391.001 us; speedup vs baseline: 1.1386x; 1.1386x over previous
//
#include <hip/hip_runtime.h>
#include <hip/hip_bf16.h>
#include <math.h>

// Problem constants (QwenAttention: B=2,S=2048,E=2048,H=16,KV=4,D=128)
#define BB 2
#define SS 2048
#define EE 2048
#define HH 16
#define KVH 4
#define DD 128

typedef short short8 __attribute__((ext_vector_type(8)));
typedef float f32x4 __attribute__((ext_vector_type(4)));

__device__ __forceinline__ unsigned int f2bf1(float x) {
    union { float f; unsigned int u; } v; v.f = x;
    return (v.u + 0x7FFFu + ((v.u >> 16) & 1u)) >> 16;  // RNE bf16
}
__device__ __forceinline__ unsigned int packbf(float a, float b) {
    return f2bf1(a) | (f2bf1(b) << 16);
}
// async global->LDS, 16B per lane
__device__ __forceinline__ void gl_lds16(const void* g, void* l) {
    __builtin_amdgcn_global_load_lds(
        (const __attribute__((address_space(1))) unsigned int*)g,
        (__attribute__((address_space(3))) unsigned int*)l,
        16, 0, 0);
}

// DPP 16-lane butterfly reductions (VALU pipe, not LDS).
#define DPPF(x, ctrl) __int_as_float(__builtin_amdgcn_update_dpp( \
    0, __float_as_int(x), ctrl, 0xf, 0xf, true))
__device__ __forceinline__ float rmax16(float x) {
    x = fmaxf(x, DPPF(x, 0xB1));
    x = fmaxf(x, DPPF(x, 0x4E));
    x = fmaxf(x, DPPF(x, 0x141));
    x = fmaxf(x, DPPF(x, 0x140));
    return x;
}
__device__ __forceinline__ float rsum16(float x) {
    x += DPPF(x, 0xB1);
    x += DPPF(x, 0x4E);
    x += DPPF(x, 0x141);
    x += DPPF(x, 0x140);
    return x;
}

// ---------------------------------------------------------------------------
// Fused fp32->bf16 conversion of all inputs + bias concat, one launch.
// ---------------------------------------------------------------------------
__global__ __launch_bounds__(256) void cvt_all_kernel(
    const float* __restrict__ x,  const float* __restrict__ Wq,
    const float* __restrict__ Wk, const float* __restrict__ Wv,
    const float* __restrict__ Wo, const float* __restrict__ bq,
    const float* __restrict__ bk, const float* __restrict__ bv,
    unsigned short* __restrict__ xb, unsigned short* __restrict__ wqkv,
    unsigned short* __restrict__ wob, float* __restrict__ bqkv)
{
    long id = (long)blockIdx.x * 256 + threadIdx.x;
    const float* src; unsigned short* dst; long j;
    if (id < 2097152)      { j = id;           src = x;  dst = xb; }
    else if (id < 3145728) { j = id - 2097152; src = Wq; dst = wqkv; }
    else if (id < 3407872) { j = id - 3145728; src = Wk; dst = wqkv + 4194304; }
    else if (id < 3670016) { j = id - 3407872; src = Wv; dst = wqkv + 5242880; }
    else if (id < 4718592) { j = id - 3670016; src = Wo; dst = wob; }
    else if (id < 4719360) {
        long c = (id - 4718592) * 4;
#pragma unroll
        for (int e = 0; e < 4; ++e) {
            long cc = c + e;
            bqkv[cc] = (cc < 2048) ? bq[cc] : (cc < 2560 ? bk[cc - 2048] : bv[cc - 2560]);
        }
        return;
    } else return;
    float4 f = ((const float4*)src)[j];
    ((uint2*)dst)[j] = make_uint2(packbf(f.x, f.y), packbf(f.z, f.w));
}

// ---------------------------------------------------------------------------
// m97-style bf16 MFMA GEMM: C[M,N] = A[M,K] @ W[N,K]^T + bias[N]  (unchanged)
// ---------------------------------------------------------------------------
template <bool OUT_BF16>
__global__ __launch_bounds__(256) void gemm_mfma_kernel(
    const unsigned short* __restrict__ A, const unsigned short* __restrict__ W,
    const float* __restrict__ bias, void* __restrict__ Cout,
    int M, int N, int K)
{
    __shared__ unsigned short As[128 * 32];
    __shared__ unsigned short Bs[128 * 32];

    const int tid  = threadIdx.x;
    const int w    = tid >> 6;
    const int lane = tid & 63;
    const int quad = lane >> 4;
    const int l16  = lane & 15;
    const int wr   = w >> 1, wc = w & 1;
    const int m0 = blockIdx.y * 128, n0 = blockIdx.x * 128;

    f32x4 acc[4][4];
#pragma unroll
    for (int i = 0; i < 4; ++i)
#pragma unroll
        for (int j = 0; j < 4; ++j) acc[i][j] = (f32x4){0.f, 0.f, 0.f, 0.f};

    const unsigned short* Ag = A + (size_t)(m0 + w * 32 + (lane >> 2)) * K + (lane & 3) * 8;
    const unsigned short* Wg = W + (size_t)(n0 + w * 32 + (lane >> 2)) * K + (lane & 3) * 8;
    unsigned short* AsB = &As[(w * 32) * 32];
    unsigned short* BsB = &Bs[(w * 32) * 32];

    for (int k0 = 0; k0 < K; k0 += 32) {
        gl_lds16(Ag + k0, AsB);
        gl_lds16(Ag + k0 + (size_t)16 * K, AsB + 16 * 32);
        gl_lds16(Wg + k0, BsB);
        gl_lds16(Wg + k0 + (size_t)16 * K, BsB + 16 * 32);
        __syncthreads();

        short8 a_f[4], b_f[4];
#pragma unroll
        for (int i = 0; i < 4; ++i)
            a_f[i] = *(const short8*)&As[(wr * 64 + i * 16 + l16) * 32 + quad * 8];
#pragma unroll
        for (int j = 0; j < 4; ++j)
            b_f[j] = *(const short8*)&Bs[(wc * 64 + j * 16 + l16) * 32 + quad * 8];
#pragma unroll
        for (int i = 0; i < 4; ++i)
#pragma unroll
            for (int j = 0; j < 4; ++j)
                acc[i][j] = __builtin_amdgcn_mfma_f32_16x16x32_bf16(a_f[i], b_f[j], acc[i][j], 0, 0, 0);
        __syncthreads();
    }

    float bj[4];
#pragma unroll
    for (int j = 0; j < 4; ++j)
        bj[j] = bias ? bias[n0 + wc * 64 + j * 16 + l16] : 0.0f;
#pragma unroll
    for (int i = 0; i < 4; ++i) {
#pragma unroll
        for (int r = 0; r < 4; ++r) {
            size_t row = m0 + wr * 64 + i * 16 + quad * 4 + r;
#pragma unroll
            for (int j = 0; j < 4; ++j) {
                size_t col = n0 + wc * 64 + j * 16 + l16;
                float val = acc[i][j][r] + bj[j];
                if (OUT_BF16)
                    ((unsigned short*)Cout)[row * N + col] = (unsigned short)f2bf1(val);
                else
                    ((float*)Cout)[row * N + col] = val;
            }
        }
    }
}

// ---------------------------------------------------------------------------
// RoPE on bf16 qkv buffer [M, 3072]  (unchanged)
// ---------------------------------------------------------------------------
__global__ __launch_bounds__(64) void rope_kernel(unsigned short* __restrict__ qkv)
{
    int bix = blockIdx.x;
    int m, col;
    if (bix < 65536) { m = bix >> 4; col = (bix & 15) * 128; }
    else { int i = bix - 65536; m = i >> 2; col = 2048 + (i & 3) * 128; }
    int s = m & (SS - 1);
    int d = threadIdx.x;
    unsigned short* p = qkv + (size_t)m * 3072 + col;
    float inv_freq = expf(-(float)d * (logf(10000.0f) / 64.0f));
    float fr = (float)s * inv_freq;
    float c = cosf(fr), sn = sinf(fr);
    union { unsigned int u; float f; } x1, x2;
    x1.u = ((unsigned int)p[d]) << 16;
    x2.u = ((unsigned int)p[d + 64]) << 16;
    p[d]      = (unsigned short)f2bf1(x1.f * c - x2.f * sn);
    p[d + 64] = (unsigned short)f2bf1(x2.f * c + x1.f * sn);
}

// ---------------------------------------------------------------------------
// Flash attention v4.1: identical structure to v4 (512 thr = 2 column-groups
// x 4 waves, BR=128, BC=128 split 64/64, pair {j,15-j} -> 17 steps/block,
// 256 blocks = 1/CU), but the group merge uses WAVE-UNIFORM branches with
// LITERAL accumulator indices. v4's runtime-indexed Oacc[s][otb+oo] demoted
// the accumulator to scratch -> 667 MB of HBM scratch traffic (R6 counters).
// ---------------------------------------------------------------------------
__global__ __launch_bounds__(512, 2) void attn_mfma_kernel(
    const unsigned short* __restrict__ qkv, unsigned short* __restrict__ o)
{
    __shared__ unsigned int Ks_u[2][64 * 64];    // 32 KB (per-group 16 KB)
    __shared__ unsigned int Vs_u[2][128 * 32];   // 32 KB (per-group 16 KB)
    __shared__ unsigned short Ps[8][32 * 64];    // 32 KB (per-wave 4 KB)
    __shared__ float Ml[2][128][2];              //  2 KB (m,l exchange)

    const int tid  = threadIdx.x;
    const int g    = tid >> 8;          // column group 0/1 (wave-uniform)
    const int tloc = tid & 255;
    const int w8   = tid >> 6;          // wave 0..7
    const int wg   = w8 & 3;            // wave within group
    const int lane = tid & 63;
    const int quad = lane >> 4;
    const int l16  = lane & 15;
    const int jp   = blockIdx.x;        // 0..7 (pair index)
    const int h    = blockIdx.y;
    const int b    = blockIdx.z;
    const int kv   = h >> 2;            // G = 4

    const float k2 = 0.12752789744920764f;  // (1/sqrt(128)) * log2(e)

    const unsigned short* kbase = qkv + (size_t)b * SS * 3072 + 2048 + kv * 128;
    const unsigned short* vbase = kbase + 512;
    unsigned int* Kg = Ks_u[g];
    unsigned int* Vg = Vs_u[g];

    const int kc  = tloc & 15;          // K chunk (8 dims)
    const int kp0 = tloc >> 4;          // K row base 0..15
    const int vpp = tloc >> 3;          // V pos-pair 0..31
    const int vd0 = (tloc & 7) * 16;    // V d-segment base

    for (int pass = 0; pass < 2; ++pass) {
        const int qt = pass ? (15 - jp) : jp;
        const int q0 = qt * 128;
        const int nt = qt + 1;          // BC=128 steps

        // ---- Q A-frags: 2 sets of 16 rows (both groups load the same Q) ----
        short8 qf[2][4];
#pragma unroll
        for (int s = 0; s < 2; ++s) {
            const unsigned short* qp =
                qkv + (size_t)(b * SS + q0 + wg * 32 + s * 16 + l16) * 3072 + h * 128 + quad * 8;
#pragma unroll
            for (int ks = 0; ks < 4; ++ks)
                qf[s][ks] = *(const short8*)(qp + ks * 32);
        }

        // ---- prefetch step 0 into regs (group's 64-col half) ----
        uint4 kpre[4], vpa[2], vpb[2];
        {
            const unsigned short* kg2 = kbase + (size_t)(g * 64 + kp0) * 3072 + kc * 8;
#pragma unroll
            for (int rr = 0; rr < 4; ++rr)
                kpre[rr] = *(const uint4*)(kg2 + (size_t)rr * 16 * 3072);
            const unsigned short* vg = vbase + (size_t)(g * 64 + 2 * vpp) * 3072 + vd0;
            vpa[0] = *(const uint4*)(vg);
            vpa[1] = *(const uint4*)(vg + 8);
            vpb[0] = *(const uint4*)(vg + 3072);
            vpb[1] = *(const uint4*)(vg + 3072 + 8);
        }

        float m_r[2][4], l_r[2][4];
        f32x4 Oacc[2][8];
#pragma unroll
        for (int s = 0; s < 2; ++s)
#pragma unroll
            for (int r = 0; r < 4; ++r) { m_r[s][r] = -1e30f; l_r[s][r] = 0.0f; }
#pragma unroll
        for (int s = 0; s < 2; ++s)
#pragma unroll
            for (int ot = 0; ot < 8; ++ot) Oacc[s][ot] = (f32x4){0.f, 0.f, 0.f, 0.f};

        for (int t = 0; t < nt; ++t) {
            __syncthreads();   // previous tile reads (or prior merge reads) done

            // ---- staged regs -> LDS (swizzled, conflict-free) ----
#pragma unroll
            for (int rr = 0; rr < 4; ++rr) {
                int pos = kp0 + rr * 16;
                int key = (kp0 + rr) & 7;
                *(uint4*)&Kg[pos * 64 + (kc ^ key) * 4] = kpre[rr];
            }
            {
                const unsigned int* pa = (const unsigned int*)vpa;
                const unsigned int* pb = (const unsigned int*)vpb;
#pragma unroll
                for (int j = 0; j < 8; ++j) {
                    unsigned lo = __builtin_amdgcn_perm(pb[j], pa[j], 0x05040100);
                    unsigned hi = __builtin_amdgcn_perm(pb[j], pa[j], 0x07060302);
                    int d0 = vd0 + 2 * j;
                    int gg = d0 >> 4;
                    int k0 = (d0 + gg) & 7;
                    int k1 = (d0 + 1 + gg) & 7;
                    Vg[d0 * 32 + (((vpp >> 2) ^ k0) & 7) * 4 + (vpp & 3)] = lo;
                    Vg[(d0 + 1) * 32 + (((vpp >> 2) ^ k1) & 7) * 4 + (vpp & 3)] = hi;
                }
            }
            __syncthreads();

            // ---- prefetch step t+1 (completes during compute) ----
            if (t + 1 < nt) {
                const unsigned short* kg2 =
                    kbase + (size_t)((t + 1) * 128 + g * 64 + kp0) * 3072 + kc * 8;
#pragma unroll
                for (int rr = 0; rr < 4; ++rr)
                    kpre[rr] = *(const uint4*)(kg2 + (size_t)rr * 16 * 3072);
                const unsigned short* vg =
                    vbase + (size_t)((t + 1) * 128 + g * 64 + 2 * vpp) * 3072 + vd0;
                vpa[0] = *(const uint4*)(vg);
                vpa[1] = *(const uint4*)(vg + 8);
                vpb[0] = *(const uint4*)(vg + 3072);
                vpb[1] = *(const uint4*)(vg + 3072 + 8);
            }

            // ---- S = Q @ K^T: both row-sets share every K-frag read ----
            f32x4 S0[4], S1[4];
#pragma unroll
            for (int ct = 0; ct < 4; ++ct) {
                f32x4 s0 = (f32x4){0.f, 0.f, 0.f, 0.f};
                f32x4 s1 = (f32x4){0.f, 0.f, 0.f, 0.f};
                const int row = ct * 16 + l16;
                const int key = (l16 + ct) & 7;
#pragma unroll
                for (int ks = 0; ks < 4; ++ks) {
                    short8 kf = *(const short8*)&Kg[row * 64 + ((ks * 4 + quad) ^ key) * 4];
                    s0 = __builtin_amdgcn_mfma_f32_16x16x32_bf16(qf[0][ks], kf, s0, 0, 0, 0);
                    s1 = __builtin_amdgcn_mfma_f32_16x16x32_bf16(qf[1][ks], kf, s1, 0, 0, 0);
                }
                S0[ct] = s0; S1[ct] = s1;
            }

            // ---- causal mask (final step only; diagonal block) ----
            if (t == nt - 1) {
                const int rw = q0 + wg * 32 + quad * 4;
#pragma unroll
                for (int ct = 0; ct < 4; ++ct) {
                    const int col = t * 128 + g * 64 + ct * 16 + l16;
#pragma unroll
                    for (int r = 0; r < 4; ++r) {
                        if (col > rw + r)      S0[ct][r] = -1e30f;
                        if (col > rw + 16 + r) S1[ct][r] = -1e30f;
                    }
                }
            }

            // ---- online softmax per set (DPP reductions) ----
#pragma unroll
            for (int s = 0; s < 2; ++s) {
                f32x4* S = s ? S1 : S0;
#pragma unroll
                for (int r = 0; r < 4; ++r) {
                    float c0 = fmaxf(fmaxf(S[0][r], S[1][r]), fmaxf(S[2][r], S[3][r]));
                    c0 = rmax16(c0);
                    float mnew = fmaxf(m_r[s][r], c0);
                    float alpha = exp2f((m_r[s][r] - mnew) * k2);
                    m_r[s][r] = mnew;
                    float mh = mnew * k2;
                    float rs = 0.0f;
                    const int prow = s * 16 + quad * 4 + r;
                    const int pkey = prow & 7;
#pragma unroll
                    for (int ct = 0; ct < 4; ++ct) {
                        float p = exp2f(S[ct][r] * k2 - mh);
                        rs += p;
                        int chunk = ct * 2 + (l16 >> 3);
                        union { float f; unsigned u; } pu; pu.f = p;
                        Ps[w8][prow * 64 + (chunk ^ pkey) * 8 + (l16 & 7)] =
                            (unsigned short)((pu.u + 0x8000u) >> 16);
                    }
                    rs = rsum16(rs);
                    l_r[s][r] = l_r[s][r] * alpha + rs;
#pragma unroll
                    for (int ot = 0; ot < 8; ++ot) Oacc[s][ot][r] *= alpha;
                }
            }

            // ---- O += P @ V: both sets share every V-frag read ----
            {
                const int pk = l16 & 7;
                short8 pf00 = *(const short8*)&Ps[w8][(l16)      * 64 + ((quad)     ^ pk) * 8];
                short8 pf01 = *(const short8*)&Ps[w8][(l16)      * 64 + ((4 + quad) ^ pk) * 8];
                short8 pf10 = *(const short8*)&Ps[w8][(16 + l16) * 64 + ((quad)     ^ pk) * 8];
                short8 pf11 = *(const short8*)&Ps[w8][(16 + l16) * 64 + ((4 + quad) ^ pk) * 8];
#pragma unroll
                for (int ot = 0; ot < 8; ++ot) {
                    const int d = ot * 16 + l16;
                    const int vkey = (l16 + ot) & 7;
                    short8 v0 = *(const short8*)&Vg[d * 32 + ((quad) ^ vkey) * 4];
                    Oacc[0][ot] = __builtin_amdgcn_mfma_f32_16x16x32_bf16(pf00, v0, Oacc[0][ot], 0, 0, 0);
                    Oacc[1][ot] = __builtin_amdgcn_mfma_f32_16x16x32_bf16(pf10, v0, Oacc[1][ot], 0, 0, 0);
                    short8 v1 = *(const short8*)&Vg[d * 32 + ((4 + quad) ^ vkey) * 4];
                    Oacc[0][ot] = __builtin_amdgcn_mfma_f32_16x16x32_bf16(pf01, v1, Oacc[0][ot], 0, 0, 0);
                    Oacc[1][ot] = __builtin_amdgcn_mfma_f32_16x16x32_bf16(pf11, v1, Oacc[1][ot], 0, 0, 0);
                }
            }
        }

        // ---- flash-merge the two groups' partials (wave-uniform branches,
        //      LITERAL Oacc indices only -> accumulator stays in registers) ----
        __syncthreads();   // all K/V LDS reads done -> reuse as exchange
        {
            // group 0 exports ot 4..7 into Ks_u region; group 1 exports ot 0..3
            // into Vs_u region.
            float* Ox = g ? (float*)Vs_u : (float*)Ks_u;
#pragma unroll
            for (int s = 0; s < 2; ++s) {
                const int row = wg * 32 + s * 16 + quad * 4;
#pragma unroll
                for (int r = 0; r < 4; ++r) {
                    if (g == 0) {
                        Ox[(row + r) * 64 +  0 + l16] = Oacc[s][4][r];
                        Ox[(row + r) * 64 + 16 + l16] = Oacc[s][5][r];
                        Ox[(row + r) * 64 + 32 + l16] = Oacc[s][6][r];
                        Ox[(row + r) * 64 + 48 + l16] = Oacc[s][7][r];
                    } else {
                        Ox[(row + r) * 64 +  0 + l16] = Oacc[s][0][r];
                        Ox[(row + r) * 64 + 16 + l16] = Oacc[s][1][r];
                        Ox[(row + r) * 64 + 32 + l16] = Oacc[s][2][r];
                        Ox[(row + r) * 64 + 48 + l16] = Oacc[s][3][r];
                    }
                    if (l16 == 0) {
                        Ml[g][row + r][0] = m_r[s][r];
                        Ml[g][row + r][1] = l_r[s][r];
                    }
                }
            }
        }
        __syncthreads();
        {
            const float* Oi = g ? (const float*)Ks_u : (const float*)Vs_u;
            const int go = 1 - g;
#pragma unroll
            for (int s = 0; s < 2; ++s) {
                const int row0 = wg * 32 + s * 16 + quad * 4;
#pragma unroll
                for (int r = 0; r < 4; ++r) {
                    const int row = row0 + r;
                    float mo  = Ml[go][row][0];
                    float lo2 = Ml[go][row][1];
                    float mm = fmaxf(m_r[s][r], mo);
                    float cw = exp2f((m_r[s][r] - mm) * k2);
                    float co = exp2f((mo - mm) * k2);
                    float inv = 1.0f / (l_r[s][r] * cw + lo2 * co);
                    unsigned short* ob =
                        o + (size_t)(b * SS + q0 + row) * 2048 + h * 128 + g * 64 + l16;
                    float own0, own1, own2, own3;
                    if (g == 0) {
                        own0 = Oacc[s][0][r]; own1 = Oacc[s][1][r];
                        own2 = Oacc[s][2][r]; own3 = Oacc[s][3][r];
                    } else {
                        own0 = Oacc[s][4][r]; own1 = Oacc[s][5][r];
                        own2 = Oacc[s][6][r]; own3 = Oacc[s][7][r];
                    }
                    ob[ 0] = (unsigned short)f2bf1((own0 * cw + Oi[row * 64 +  0 + l16] * co) * inv);
                    ob[16] = (unsigned short)f2bf1((own1 * cw + Oi[row * 64 + 16 + l16] * co) * inv);
                    ob[32] = (unsigned short)f2bf1((own2 * cw + Oi[row * 64 + 32 + l16] * co) * inv);
                    ob[48] = (unsigned short)f2bf1((own3 * cw + Oi[row * 64 + 48 + l16] * co) * inv);
                }
            }
        }
        // loop-top __syncthreads() protects exchange region before next pass
    }
}

// ---------------------------------------------------------------------------
extern "C" void kernel_launch(void* const* d_in, const int* in_sizes, int n_in,
                              void* d_out, int out_size, void* d_ws, size_t ws_size,
                              hipStream_t stream)
{
    const float* x  = (const float*)d_in[0];
    const float* Wq = (const float*)d_in[1];
    const float* bq = (const float*)d_in[2];
    const float* Wk = (const float*)d_in[3];
    const float* bk = (const float*)d_in[4];
    const float* Wv = (const float*)d_in[5];
    const float* bv = (const float*)d_in[6];
    const float* Wo = (const float*)d_in[7];
    float* out = (float*)d_out;

    const int M = BB * SS;  // 4096
    char* wsb = (char*)d_ws;
    unsigned short* xb   = (unsigned short*)wsb;  wsb += (size_t)M * EE * 2;
    unsigned short* wqkv = (unsigned short*)wsb;  wsb += (size_t)3072 * EE * 2;
    unsigned short* wob  = (unsigned short*)wsb;  wsb += (size_t)EE * EE * 2;
    unsigned short* qkvb = (unsigned short*)wsb;  wsb += (size_t)M * 3072 * 2;
    unsigned short* abb  = (unsigned short*)wsb;  wsb += (size_t)M * 2048 * 2;
    float* bqkv = (float*)wsb;

    cvt_all_kernel<<<18435, 256, 0, stream>>>(x, Wq, Wk, Wv, Wo, bq, bk, bv,
                                              xb, wqkv, wob, bqkv);

    gemm_mfma_kernel<true><<<dim3(3072 / 128, M / 128), 256, 0, stream>>>(
        xb, wqkv, bqkv, qkvb, M, 3072, EE);

    rope_kernel<<<M * HH + M * KVH, 64, 0, stream>>>(qkvb);

    // flash attention: 8 balanced q-tile pairs x 16 heads x 2 batch, 512 thr
    attn_mfma_kernel<<<dim3(8, HH, BB), 512, 0, stream>>>(qkvb, abb);

    gemm_mfma_kernel<false><<<dim3(EE / 128, M / 128), 256, 0, stream>>>(
        abb, wob, nullptr, out, M, EE, 2048);
}